// Round 3
// baseline (346.931 us; speedup 1.0000x reference)
//
#include <hip/hip_runtime.h>
#include <hip/hip_bf16.h>

#define BATCH 8192
#define IDIM 256
#define ODIM 256
#define KGRID 64

#define BM 128
#define THREADS 512
#define RG_TOT 4096       // (2*IDIM*KGRID)/8

typedef __attribute__((ext_vector_type(8))) short short8;
typedef __attribute__((ext_vector_type(4))) float float4v;
typedef __attribute__((ext_vector_type(4))) unsigned int uint4v;

// pack two f32 -> (bf16(c) | bf16(s)<<16), RTNE
__device__ __forceinline__ unsigned int bf16pack(float c, float s) {
    union { float f; unsigned int u; } a, b;
    a.f = c; b.f = s;
    unsigned int ua = a.u + (0x7fffu + ((a.u >> 16) & 1u));
    unsigned int ub = b.u + (0x7fffu + ((b.u >> 16) & 1u));
    return (ua >> 16) | (ub & 0xffff0000u);
}

// W[2][256][256][64] f32  ->  Bw[rg=4096][j=256][8] bf16
// read-coalesced (consecutive lanes -> consecutive rg); strided 16B stores are
// L2-absorbed (Bw is 16.8MB, L2-resident for the immediately-following GEMM).
__global__ void prep_w(const float4v* __restrict__ W, uint4v* __restrict__ Bw) {
    int tid = blockIdx.x * 256 + threadIdx.x;   // 1,048,576 threads
    int rg = tid & 4095;
    int j = tid >> 12;
    float4v c4 = W[j * 4096 + rg];
    float4v s4 = W[1048576 + j * 4096 + rg];
    uint4v o;
    o.x = bf16pack(c4.x, s4.x);
    o.y = bf16pack(c4.y, s4.y);
    o.z = bf16pack(c4.z, s4.z);
    o.w = bf16pack(c4.w, s4.w);
    Bw[rg * 256 + j] = o;
}

// load one half-iteration (2 k-slots x 4 col-groups) of B into register buffer B
#define LOADHALF(B, S0) do {                                              \
    _Pragma("unroll") for (int q_ = 0; q_ < 2; ++q_) {                    \
        int s_ = (S0) + q_; if (s_ > SMAX - 1) s_ = SMAX - 1;             \
        _Pragma("unroll") for (int f_ = 0; f_ < 4; ++f_)                  \
            B[q_ * 4 + f_] = Bp[(size_t)s_ * 1024 + f_ * 16];             \
    } } while (0)

template<int NC>
__global__ __launch_bounds__(THREADS, 4) void kan_main(
    const float* __restrict__ x,
    const short* __restrict__ Bw,
    float* __restrict__ part)
{
    constexpr int IPC = 256 / NC;       // i-values per K-chunk
    constexpr int SMAX = IPC * 4;       // k-steps per chunk
    constexpr int RGC = IPC * 16;       // rg per chunk
    constexpr int LOG = (NC == 8) ? 3 : 2;

    __shared__ __align__(16) short A_lds[2][16 * BM * 8];   // 64 KB, dbuf feature tiles

    const int bx = blockIdx.x;
    const int chunk = bx & (NC - 1);   // K-chunk; == XCD id when grid%8==0
    const int mt = bx >> LOG;          // M-tile 0..63
    const int b0 = mt * BM;
    const int i0 = chunk * IPC;
    const int t = threadIdx.x;
    const int lane = t & 63;
    const int wave = t >> 6;           // 0..7
    const int wm = wave >> 2;          // 0..1  (M half)
    const int wn = wave & 3;           // 0..3  (N quarter)

    const int row = t >> 2;            // 0..127  (feats row)
    const int sub = t & 3;             // 16 consecutive k's per thread

    const float* xp = x + (size_t)(b0 + row) * IDIM + i0;

    // features for one i -> Abuf laid out [16 rg][128 row][8 bf16]
    auto feats = [&](short* Abuf, float xv) {
        float xk = xv * 0.15915494309189535f;   // revolutions per unit k
        float dr = xk - floorf(xk);
        float cd = __builtin_amdgcn_cosf(dr);   // cos(2*pi*x)
        float sd = __builtin_amdgcn_sinf(dr);
        float r0 = xk * (float)(sub * 16 + 1);
        r0 -= floorf(r0);
        float c = __builtin_amdgcn_cosf(r0);
        float s = __builtin_amdgcn_sinf(r0);
        uint4v* slotp = (uint4v*)Abuf + (sub * 4) * BM + row;
        #pragma unroll
        for (int g = 0; g < 4; ++g) {
            uint4v o;
            #pragma unroll
            for (int u = 0; u < 4; ++u) {
                union { __hip_bfloat162 h; unsigned int w; } cv;
                cv.h = __float22bfloat162_rn(make_float2(c, s));
                o[u] = cv.w;
                float cn = c * cd - s * sd;     // advance angle by x
                float sn = s * cd + c * sd;
                c = cn; s = sn;
            }
            slotp[g * BM] = o;
        }
    };

    // per-thread B pointer (16B slot granularity): slot = rg*256 + col
    const short8* Bp = (const short8*)Bw
        + (size_t)(chunk * RGC + (lane >> 4)) * 256 + wn * 64 + (lane & 15);

    short8 bB[2][8];
    LOADHALF(bB[0], 0);   // s = 0,1  (iter 0, kk 0..1)
    LOADHALF(bB[1], 2);   // s = 2,3  (iter 0, kk 2..3)

    float xv = xp[0];
    feats(A_lds[0], xv);
    xv = xp[1];
    __syncthreads();

    float4v acc[4][4];
    #pragma unroll
    for (int m = 0; m < 4; ++m)
        #pragma unroll
        for (int f = 0; f < 4; ++f)
            acc[m][f] = (float4v)(0.0f);

    const int aoff = (lane >> 4) * BM + wm * 64 + (lane & 15);

    for (int it = 0; it < IPC; ++it) {
        const int cur = it & 1;
        const short8* Ab = (const short8*)A_lds[cur];
        #pragma unroll
        for (int kk = 0; kk < 4; ++kk) {
            short8 a[4];
            #pragma unroll
            for (int m = 0; m < 4; ++m)
                a[m] = Ab[(kk * 4) * BM + aoff + m * 16];
            #pragma unroll
            for (int m = 0; m < 4; ++m)
                #pragma unroll
                for (int f = 0; f < 4; ++f)
                    acc[m][f] = __builtin_amdgcn_mfma_f32_16x16x32_bf16(
                        a[m], bB[kk >> 1][(kk & 1) * 4 + f], acc[m][f], 0, 0, 0);
            if (kk == 1) { LOADHALF(bB[0], it * 4 + 4); }   // next iter kk 0..1
            if (kk == 3) { LOADHALF(bB[1], it * 4 + 6); }   // next iter kk 2..3
        }
        if (it + 1 < IPC) {
            feats(A_lds[cur ^ 1], xv);
            xv = xp[(it + 2 < IPC) ? (it + 2) : (IPC - 1)];
        }
        __syncthreads();
    }

    // ---- store partials: part[chunk][b][j] ----
    // C/D layout (m89): col = lane&15, row = (lane>>4)*4 + v
    float* pc = part + (size_t)chunk * (BATCH * ODIM)
              + (size_t)(b0 + wm * 64 + ((lane >> 4) * 4)) * ODIM
              + wn * 64 + (lane & 15);
    #pragma unroll
    for (int m = 0; m < 4; ++m)
        #pragma unroll
        for (int v = 0; v < 4; ++v)
            #pragma unroll
            for (int f = 0; f < 4; ++f)
                pc[(size_t)(m * 16 + v) * ODIM + f * 16] = acc[m][f][v];
}

template<int NC>
__global__ void reduce_bias(const float4v* __restrict__ part,
                            const float4v* __restrict__ bias,
                            float4v* __restrict__ out)
{
    const int tid = blockIdx.x * 256 + threadIdx.x;   // 524288 float4s
    const int Q = BATCH * ODIM / 4;
    float4v r = part[tid];
    #pragma unroll
    for (int c = 1; c < NC; ++c) r += part[tid + c * Q];
    r += bias[tid & 63];
    out[tid] = r;
}

extern "C" void kernel_launch(void* const* d_in, const int* in_sizes, int n_in,
                              void* d_out, int out_size, void* d_ws, size_t ws_size,
                              hipStream_t stream)
{
    const float* x = (const float*)d_in[0];
    const float* W = (const float*)d_in[1];
    const float* bias = (const float*)d_in[2];
    float* out = (float*)d_out;

    const size_t bw_bytes = (size_t)RG_TOT * 256 * 16;          // 16.78 MB
    const size_t part_bytes8 = (size_t)8 * BATCH * ODIM * 4;    // 67.1 MB

    short* Bw = (short*)d_ws;
    float* part = (float*)((char*)d_ws + bw_bytes);

    prep_w<<<4096, 256, 0, stream>>>((const float4v*)W, (uint4v*)Bw);

    if (ws_size >= bw_bytes + part_bytes8) {
        // 8-way split-K: 512 blocks = 2 blocks/CU; each XCD owns one B-chunk
        kan_main<8><<<512, THREADS, 0, stream>>>(x, Bw, part);
        reduce_bias<8><<<(BATCH * ODIM / 4) / 256, 256, 0, stream>>>(
            (const float4v*)part, (const float4v*)bias, (float4v*)out);
    } else {
        kan_main<4><<<256, THREADS, 0, stream>>>(x, Bw, part);
        reduce_bias<4><<<(BATCH * ODIM / 4) / 256, 256, 0, stream>>>(
            (const float4v*)part, (const float4v*)bias, (float4v*)out);
    }
}

// Round 4
// 223.062 us; speedup vs baseline: 1.5553x; 1.5553x over previous
//
#include <hip/hip_runtime.h>
#include <hip/hip_bf16.h>

#define BATCH 8192
#define IDIM 256
#define ODIM 256
#define KGRID 64

#define NC 4
#define IPC 64            // i-values per K-chunk
#define BM 64
#define THREADS 512
#define RG_TOT 4096       // (2*IDIM*KGRID)/8

typedef __attribute__((ext_vector_type(8))) short short8;
typedef __attribute__((ext_vector_type(4))) float float4v;
typedef __attribute__((ext_vector_type(16))) float float16v;
typedef __attribute__((ext_vector_type(4))) unsigned int uint4v;

// pack two f32 -> (bf16(c) | bf16(s)<<16), RTNE
__device__ __forceinline__ unsigned int bf16pack(float c, float s) {
    union { float f; unsigned int u; } a, b;
    a.f = c; b.f = s;
    unsigned int ua = a.u + (0x7fffu + ((a.u >> 16) & 1u));
    unsigned int ub = b.u + (0x7fffu + ((b.u >> 16) & 1u));
    return (ua >> 16) | (ub & 0xffff0000u);
}

// W[2][256][256][64] f32  ->  Bw[rg=4096][j=256][8] bf16, read-coalesced
__global__ void prep_w(const float4v* __restrict__ W, uint4v* __restrict__ Bw) {
    int tid = blockIdx.x * 256 + threadIdx.x;   // 1,048,576 threads
    int rg = tid & 4095;
    int j = tid >> 12;
    float4v c4 = W[j * 4096 + rg];
    float4v s4 = W[1048576 + j * 4096 + rg];
    uint4v o;
    o.x = bf16pack(c4.x, s4.x);
    o.y = bf16pack(c4.y, s4.y);
    o.z = bf16pack(c4.z, s4.z);
    o.w = bf16pack(c4.w, s4.w);
    Bw[rg * 256 + j] = o;
}

__global__ __launch_bounds__(THREADS, 4) void kan_main(
    const float* __restrict__ x,
    const short* __restrict__ Bw,
    float* __restrict__ part)
{
    // [buf][ (i2*16 + rg16)*64 + row ]  uint4 slots; 64 KB total
    __shared__ __align__(16) uint4v A_lds[2][2048];

    const int bx = blockIdx.x;
    const int chunk = bx & 3;          // K-chunk; XCD (bx&7) sees one chunk
    const int mt = bx >> 2;            // M-tile 0..127
    const int b0 = mt * BM;
    const int i0 = chunk * IPC;
    const int t = threadIdx.x;
    const int lane = t & 63;
    const int wave = t >> 6;           // 0..7
    const int wm = wave >> 2;          // 0..1  (32-row half)
    const int wn = wave & 3;           // 0..3  (64-col quarter)

    // x: one row per lane
    const float* xp = x + (size_t)(b0 + lane) * IDIM + i0;

    // feats for one i: wave covers k codes wave*8 .. wave*8+7 for ALL 64 rows
    // (lane = row). Writes 2 uint4 slots: rg16 = wave*2 + g.
    auto feats = [&](uint4v* buf, int rgb, float xv) {
        float xk = xv * 0.15915494309189535f;   // revolutions per unit k
        float dr = xk - floorf(xk);
        float cd = __builtin_amdgcn_cosf(dr);   // cos(2*pi*x)
        float sd = __builtin_amdgcn_sinf(dr);
        float r0 = xk * (float)(wave * 8 + 1);
        r0 -= floorf(r0);
        float c = __builtin_amdgcn_cosf(r0);
        float s = __builtin_amdgcn_sinf(r0);
        #pragma unroll
        for (int g = 0; g < 2; ++g) {
            uint4v o;
            #pragma unroll
            for (int u = 0; u < 4; ++u) {
                union { __hip_bfloat162 h; unsigned int w; } cv;
                cv.h = __float22bfloat162_rn(make_float2(c, s));
                o[u] = cv.w;
                float cn = c * cd - s * sd;     // advance angle by x
                float sn = s * cd + c * sd;
                c = cn; s = sn;
            }
            buf[(rgb + wave * 2 + g) * 64 + lane] = o;
        }
    };

    // B slot = rg*256 + col ; lane's B-frag: rg = step*2 + (lane>>5),
    // col = wn*64 + f*32 + (lane&31)
    const short8* Bp = (const short8*)Bw
        + ((size_t)(chunk * 1024 + (lane >> 5))) * 256 + wn * 64 + (lane & 31);

    short8 bB[2][2];
    bB[0][0] = Bp[0];
    bB[0][1] = Bp[32];

    float2 xv2 = *(const float2*)xp;        // i = 0,1
    feats(&A_lds[0][0], 0, xv2.x);
    feats(&A_lds[0][0], 16, xv2.y);
    xv2 = *(const float2*)(xp + 2);
    __syncthreads();

    float16v acc[2];
    acc[0] = (float16v)(0.0f);
    acc[1] = (float16v)(0.0f);

    // A slot: (hs*2 + (lane>>5))*64 + wm*32 + (lane&31)
    const int aoff = (lane >> 5) * 64 + wm * 32 + (lane & 31);

    for (int phase = 0; phase < 32; ++phase) {
        const short8* Ab = (const short8*)&A_lds[phase & 1][0];
        #pragma unroll
        for (int hs = 0; hs < 16; ++hs) {     // 2 i's x 8 k-steps
            const int p = hs & 1;
            // prefetch next step's B (clamped on the very last step)
            const short8* Bq = (hs == 15 && phase == 31) ? Bp : (Bp + 512);
            bB[p ^ 1][0] = Bq[0];
            bB[p ^ 1][1] = Bq[32];
            short8 a = Ab[(hs * 2) * 64 + aoff];
            acc[0] = __builtin_amdgcn_mfma_f32_32x32x16_bf16(a, bB[p][0], acc[0], 0, 0, 0);
            acc[1] = __builtin_amdgcn_mfma_f32_32x32x16_bf16(a, bB[p][1], acc[1], 0, 0, 0);
            Bp = Bq;
        }
        if (phase < 31) {
            uint4v* nb = &A_lds[(phase & 1) ^ 1][0];
            feats(nb, 0, xv2.x);
            feats(nb, 16, xv2.y);
            int nl = phase * 2 + 4;           // next-next phase's first i
            if (nl > 62) nl = 62;
            xv2 = *(const float2*)(xp + nl);
        }
        __syncthreads();
    }

    // ---- store partials: part[chunk][b][j] ----
    // 32x32 C/D layout (m74/m101): col = lane&31, row = (v&3)+8*(v>>2)+4*(lane>>5)
    const int cb = wn * 64 + (lane & 31);
    const int rb = b0 + wm * 32 + 4 * (lane >> 5);
    float* pc = part + (size_t)chunk * (BATCH * ODIM);
    #pragma unroll
    for (int f = 0; f < 2; ++f)
        #pragma unroll
        for (int v = 0; v < 16; ++v) {
            int r = rb + (v & 3) + 8 * (v >> 2);
            pc[(size_t)r * ODIM + cb + f * 32] = acc[f][v];
        }
}

__global__ void reduce_bias(const float4v* __restrict__ part,
                            const float4v* __restrict__ bias,
                            float4v* __restrict__ out)
{
    const int tid = blockIdx.x * 256 + threadIdx.x;   // 524288 float4s
    const int Q = BATCH * ODIM / 4;
    float4v r = part[tid];
    #pragma unroll
    for (int c = 1; c < NC; ++c) r += part[tid + c * Q];
    r += bias[tid & 63];
    out[tid] = r;
}

extern "C" void kernel_launch(void* const* d_in, const int* in_sizes, int n_in,
                              void* d_out, int out_size, void* d_ws, size_t ws_size,
                              hipStream_t stream)
{
    const float* x = (const float*)d_in[0];
    const float* W = (const float*)d_in[1];
    const float* bias = (const float*)d_in[2];
    float* out = (float*)d_out;

    const size_t bw_bytes = (size_t)RG_TOT * 256 * 16;   // 16.78 MB

    short* Bw = (short*)d_ws;
    float* part = (float*)((char*)d_ws + bw_bytes);      // NC*8.4 MB

    prep_w<<<4096, 256, 0, stream>>>((const float4v*)W, (uint4v*)Bw);
    // 512 blocks = 2 blocks/CU (64 KB LDS, <=128 regs/wave)
    kan_main<<<(BATCH / BM) * NC, THREADS, 0, stream>>>(x, Bw, part);
    reduce_bias<<<(BATCH * ODIM / 4) / 256, 256, 0, stream>>>(
        (const float4v*)part, (const float4v*)bias, (float4v*)out);
}

// Round 5
// 197.679 us; speedup vs baseline: 1.7550x; 1.1284x over previous
//
#include <hip/hip_runtime.h>
#include <hip/hip_bf16.h>

#define BATCH 8192
#define IDIM 256
#define ODIM 256

#define NC 8
#define IPC 32            // i-values per K-chunk
#define BM 128            // rows per block
#define THREADS 256
#define RG_TOT 4096       // (2*IDIM*KGRID)/8

typedef __attribute__((ext_vector_type(8))) short short8;
typedef __attribute__((ext_vector_type(4))) float float4v;
typedef __attribute__((ext_vector_type(4))) unsigned int uint4v;

#define INV2PI 0.15915494309189535f

// pack two f32 -> (bf16(c) | bf16(s)<<16), RTNE
__device__ __forceinline__ unsigned int bf16pack(float c, float s) {
    union { float f; unsigned int u; } a, b;
    a.f = c; b.f = s;
    unsigned int ua = a.u + (0x7fffu + ((a.u >> 16) & 1u));
    unsigned int ub = b.u + (0x7fffu + ((b.u >> 16) & 1u));
    return (ua >> 16) | (ub & 0xffff0000u);
}

// W[2][256][256][64] f32  ->  Bw[rg=4096][j=256][8] bf16, read-coalesced
__global__ void prep_w(const float4v* __restrict__ W, uint4v* __restrict__ Bw) {
    int tid = blockIdx.x * 256 + threadIdx.x;   // 1,048,576 threads
    int rg = tid & 4095;
    int j = tid >> 12;
    float4v c4 = W[j * 4096 + rg];
    float4v s4 = W[1048576 + j * 4096 + rg];
    uint4v o;
    o.x = bf16pack(c4.x, s4.x);
    o.y = bf16pack(c4.y, s4.y);
    o.z = bf16pack(c4.z, s4.z);
    o.w = bf16pack(c4.w, s4.w);
    Bw[rg * 256 + j] = o;
}

// 4 waves (2M x 2N), wave tile 64x64, block tile 128 rows x 128 cols.
// 12 waves/CU (3 blocks) at the 170-reg step: acc 64 AGPR + ~76 VGPR ~= 140.
__global__ __launch_bounds__(THREADS, 3) void kan_main(
    const float* __restrict__ x,
    const short* __restrict__ Bw,
    float* __restrict__ part)
{
    // half-i slab: [8 rg][130 row-slots] uint4; rg stride 2080B == 8 dwords
    // mod 32 banks -> ds_read groups shift 0/8/16/24 (conflict-free).
    __shared__ __align__(16) uint4v A_lds[2][8 * 130];

    const int bx = blockIdx.x;
    const int chunk = bx & 7;          // K-chunk == XCD id (1024 blocks)
    const int nt = (bx >> 3) & 1;      // N half
    const int mt = bx >> 4;            // M-tile 0..63
    const int b0 = mt * BM;
    const int i0 = chunk * IPC;
    const int t = threadIdx.x;
    const int lane = t & 63;
    const int wave = t >> 6;           // 0..3
    const int wm = wave >> 1;          // 0..1  (64-row half)
    const int wn = wave & 1;           // 0..1  (64-col half)

    const int frow = t & 127;          // feats row
    const int fsub = t >> 7;           // 0..1 (16 codes each)

    const float* xp = x + (size_t)(b0 + frow) * IDIM + i0;

    // feats for one (i, h): thread covers codes h*32 + fsub*16 .. +15 for its row
    auto feats = [&](uint4v* buf, float xk, float cd, float sd, int h) {
        const int c0 = h * 32 + fsub * 16;
        float r0 = xk * (float)(c0 + 1);
        r0 -= floorf(r0);
        float c = __builtin_amdgcn_cosf(r0);
        float s = __builtin_amdgcn_sinf(r0);
        uint4v* sl = buf + (fsub * 4) * 130 + frow;
        #pragma unroll
        for (int q = 0; q < 4; ++q) {
            uint4v o;
            #pragma unroll
            for (int e = 0; e < 4; ++e) {
                union { __hip_bfloat162 h2; unsigned int w; } cv;
                cv.h2 = __float22bfloat162_rn(make_float2(c, s));
                o[e] = cv.w;
                float cn = c * cd - s * sd;     // advance angle by x
                float sn = s * cd + c * sd;
                c = cn; s = sn;
            }
            sl[q * 130] = o;
        }
    };

    // B slot = rg*256 + col; rg = chunk*512 + s*4 + (lane>>4);
    // col = nt*128 + wn*64 + f*16 + (lane&15)
    const short8* Bp = (const short8*)Bw
        + (size_t)(chunk * 512 + (lane >> 4)) * 256
        + nt * 128 + wn * 64 + (lane & 15);

    short8 bB[2][4];
    #pragma unroll
    for (int f = 0; f < 4; ++f) bB[0][f] = Bp[f * 16];

    float xcur = xp[0];
    float xnext = xp[1];
    float xk = xcur * INV2PI;
    float dr = xk - floorf(xk);
    float cd = __builtin_amdgcn_cosf(dr);
    float sd = __builtin_amdgcn_sinf(dr);
    feats(&A_lds[0][0], xk, cd, sd, 0);
    __syncthreads();

    float4v acc[4][4];
    #pragma unroll
    for (int m = 0; m < 4; ++m)
        #pragma unroll
        for (int f = 0; f < 4; ++f)
            acc[m][f] = (float4v)(0.0f);

    const int arow = wm * 64 + (lane & 15);
    const int ag = lane >> 4;

    // phase p = (i = p>>1, h = p&1); 2 k-steps (K=32) per phase
    for (int p = 0; p < 64; ++p) {
        const short8* Ab = (const short8*)&A_lds[p & 1][0];
        const int s = p * 2;
        #pragma unroll
        for (int kk = 0; kk < 2; ++kk) {
            int sn = s + kk + 1; if (sn > 127) sn = 127;   // prefetch step
            #pragma unroll
            for (int f = 0; f < 4; ++f)
                bB[kk ^ 1][f] = Bp[(size_t)sn * 1024 + f * 16];
            short8 a[4];
            #pragma unroll
            for (int m = 0; m < 4; ++m)
                a[m] = Ab[(kk * 4 + ag) * 130 + arow + m * 16];
            #pragma unroll
            for (int m = 0; m < 4; ++m)
                #pragma unroll
                for (int f = 0; f < 4; ++f)
                    acc[m][f] = __builtin_amdgcn_mfma_f32_16x16x32_bf16(
                        a[m], bB[kk][f], acc[m][f], 0, 0, 0);
        }
        if (p < 63) {
            const int pn = p + 1;
            if ((pn & 1) == 0) {          // next phase starts a new i
                xcur = xnext;
                const int inew = pn >> 1;
                if (inew < IPC - 1) xnext = xp[inew + 1];
                xk = xcur * INV2PI;
                dr = xk - floorf(xk);
                cd = __builtin_amdgcn_cosf(dr);
                sd = __builtin_amdgcn_sinf(dr);
            }
            feats(&A_lds[pn & 1][0], xk, cd, sd, pn & 1);
        }
        __syncthreads();
    }

    // ---- store partials: part[chunk][b][j] ----
    // 16x16 C/D layout (m89): col = lane&15, row = (lane>>4)*4 + v
    float* pc = part + (size_t)chunk * (BATCH * ODIM)
              + (size_t)(b0 + wm * 64 + (lane >> 4) * 4) * ODIM
              + nt * 128 + wn * 64 + (lane & 15);
    #pragma unroll
    for (int m = 0; m < 4; ++m)
        #pragma unroll
        for (int v = 0; v < 4; ++v)
            #pragma unroll
            for (int f = 0; f < 4; ++f)
                pc[(size_t)(m * 16 + v) * ODIM + f * 16] = acc[m][f][v];
}

__global__ void reduce_bias(const float4v* __restrict__ part,
                            const float4v* __restrict__ bias,
                            float4v* __restrict__ out)
{
    const int tid = blockIdx.x * 256 + threadIdx.x;   // 524288 float4s
    const int Q = BATCH * ODIM / 4;
    float4v r = part[tid];
    #pragma unroll
    for (int c = 1; c < NC; ++c) r += part[tid + c * Q];
    r += bias[tid & 63];
    out[tid] = r;
}

extern "C" void kernel_launch(void* const* d_in, const int* in_sizes, int n_in,
                              void* d_out, int out_size, void* d_ws, size_t ws_size,
                              hipStream_t stream)
{
    const float* x = (const float*)d_in[0];
    const float* W = (const float*)d_in[1];
    const float* bias = (const float*)d_in[2];
    float* out = (float*)d_out;

    const size_t bw_bytes = (size_t)RG_TOT * 256 * 16;   // 16.78 MB

    short* Bw = (short*)d_ws;
    float* part = (float*)((char*)d_ws + bw_bytes);      // 67.1 MB (ws>=84MB proven R3)

    prep_w<<<4096, 256, 0, stream>>>((const float4v*)W, (uint4v*)Bw);
    // 1024 blocks = 3 blocks/CU (33.3 KB LDS, 170-reg step)
    kan_main<<<(BATCH / BM) * 2 * NC, THREADS, 0, stream>>>(x, Bw, part);
    reduce_bias<<<(BATCH * ODIM / 4) / 256, 256, 0, stream>>>(
        (const float4v*)part, (const float4v*)bias, (float4v*)out);
}

// Round 7
// 174.582 us; speedup vs baseline: 1.9872x; 1.1323x over previous
//
#include <hip/hip_runtime.h>
#include <hip/hip_bf16.h>

#define BATCH 8192
#define IDIM 256
#define ODIM 256

#define NC 8
#define IPC 32            // i-values per K-chunk
#define BM 128            // rows per block
#define THREADS 512
#define RG_TOT 4096       // (2*IDIM*KGRID)/8
#define RS 131            // uint4-slot stride between rg rows (>=128 rows, odd pad)

typedef __attribute__((ext_vector_type(8))) short short8;
typedef __attribute__((ext_vector_type(4))) float float4v;
typedef __attribute__((ext_vector_type(16))) float float16v;
typedef __attribute__((ext_vector_type(4))) unsigned int uint4v;

#define INV2PI 0.15915494309189535f

// pack two f32 -> (bf16(c) | bf16(s)<<16), RTNE
__device__ __forceinline__ unsigned int bf16pack(float c, float s) {
    union { float f; unsigned int u; } a, b;
    a.f = c; b.f = s;
    unsigned int ua = a.u + (0x7fffu + ((a.u >> 16) & 1u));
    unsigned int ub = b.u + (0x7fffu + ((b.u >> 16) & 1u));
    return (ua >> 16) | (ub & 0xffff0000u);
}

// W[2][256][256][64] f32  ->  Bw[rg=4096][j=256][8] bf16, read-coalesced
__global__ void prep_w(const float4v* __restrict__ W, uint4v* __restrict__ Bw) {
    int tid = blockIdx.x * 256 + threadIdx.x;   // 1,048,576 threads
    int rg = tid & 4095;
    int j = tid >> 12;
    float4v c4 = W[j * 4096 + rg];
    float4v s4 = W[1048576 + j * 4096 + rg];
    uint4v o;
    o.x = bf16pack(c4.x, s4.x);
    o.y = bf16pack(c4.y, s4.y);
    o.z = bf16pack(c4.z, s4.z);
    o.w = bf16pack(c4.w, s4.w);
    Bw[rg * 256 + j] = o;
}

// 8 waves (2M x 4N), wave tile 64x64 via 32x32x16 MFMA (acc = 64 AGPR,
// B dbuf = 16 VGPR) -> ~120 unified regs: fits 4 waves/SIMD = 2 blocks/CU.
__global__ __launch_bounds__(THREADS, 4) void kan_main(
    const float* __restrict__ x,
    const short* __restrict__ Bw,
    float* __restrict__ part)
{
    // per-i slab: [16 rg][RS=131 row-slots] uint4 = 32.75 KB; dbuf 65.5 KB
    __shared__ __align__(16) uint4v A_lds[2][16 * RS];

    const int bx = blockIdx.x;
    const int chunk = bx & 7;          // K-chunk == XCD id (512 blocks)
    const int mt = bx >> 3;            // M-tile 0..63
    const int b0 = mt * BM;
    const int i0 = chunk * IPC;
    const int t = threadIdx.x;
    const int lane = t & 63;
    const int wave = t >> 6;           // 0..7
    const int wm = wave >> 2;          // 0..1  (64-row half)
    const int wn = wave & 3;           // 0..3  (64-col quarter)

    const int frow = t >> 2;           // 0..127 feats row
    const int fsub = t & 3;            // 16 consecutive codes per thread

    const float* xp = x + (size_t)(b0 + frow) * IDIM + i0;

    // features for one i: thread covers codes fsub*16 .. +15 of its row
    auto feats = [&](uint4v* buf, float xk, float cd, float sd) {
        float r0 = xk * (float)(fsub * 16 + 1);
        r0 -= floorf(r0);
        float c = __builtin_amdgcn_cosf(r0);
        float s = __builtin_amdgcn_sinf(r0);
        uint4v* sl = buf + (fsub * 4) * RS + frow;
        #pragma unroll
        for (int q = 0; q < 4; ++q) {
            uint4v o;
            #pragma unroll
            for (int e = 0; e < 4; ++e) {
                union { __hip_bfloat162 h2; unsigned int w; } cv;
                cv.h2 = __float22bfloat162_rn(make_float2(c, s));
                o[e] = cv.w;
                float cn = c * cd - s * sd;     // advance angle by x
                float sn = s * cd + c * sd;
                c = cn; s = sn;
            }
            sl[q * RS] = o;
        }
    };

    // B slot = rg*256 + col; rg = chunk*512 + i*16 + ks*2 + (lane>>5);
    // col = wn*64 + f*32 + (lane&31)   (layout verified in R4)
    const short8* Bp = (const short8*)Bw
        + (size_t)(chunk * 512 + (lane >> 5)) * 256 + wn * 64 + (lane & 31);

    short8 bB[2][2];
    bB[0][0] = Bp[0];
    bB[0][1] = Bp[32];

    float xcur = xp[0];
    float xnext = xp[1];
    float xk = xcur * INV2PI;
    float dr = xk - floorf(xk);
    float cd = __builtin_amdgcn_cosf(dr);
    float sd = __builtin_amdgcn_sinf(dr);
    feats(&A_lds[0][0], xk, cd, sd);
    __syncthreads();

    float16v acc[2][2];
    acc[0][0] = (float16v)(0.0f);
    acc[0][1] = (float16v)(0.0f);
    acc[1][0] = (float16v)(0.0f);
    acc[1][1] = (float16v)(0.0f);

    // A slot: (ks*2 + (lane>>5))*RS + wm*64 + rt*32 + (lane&31)
    const int abase = (lane >> 5) * RS + wm * 64 + (lane & 31);

    for (int p = 0; p < IPC; ++p) {
        const short8* Ab = (const short8*)&A_lds[p & 1][0];
        const int bO = p * 4096;               // i advance = 16 rg = 4096 B-slots
        #pragma unroll
        for (int ks = 0; ks < 8; ++ks) {
            int noff = bO + (ks + 1) * 512;    // prefetch next k-step
            if (p == IPC - 1 && ks == 7) noff = bO + ks * 512;   // clamp (discarded)
            bB[(ks + 1) & 1][0] = Bp[noff];
            bB[(ks + 1) & 1][1] = Bp[noff + 32];
            short8 a0 = Ab[(ks * 2) * RS + abase];
            short8 a1 = Ab[(ks * 2) * RS + abase + 32];
            acc[0][0] = __builtin_amdgcn_mfma_f32_32x32x16_bf16(a0, bB[ks & 1][0], acc[0][0], 0, 0, 0);
            acc[1][0] = __builtin_amdgcn_mfma_f32_32x32x16_bf16(a1, bB[ks & 1][0], acc[1][0], 0, 0, 0);
            acc[0][1] = __builtin_amdgcn_mfma_f32_32x32x16_bf16(a0, bB[ks & 1][1], acc[0][1], 0, 0, 0);
            acc[1][1] = __builtin_amdgcn_mfma_f32_32x32x16_bf16(a1, bB[ks & 1][1], acc[1][1], 0, 0, 0);
        }
        if (p < IPC - 1) {
            xcur = xnext;
            xnext = xp[(p + 2 < IPC) ? (p + 2) : (IPC - 1)];
            xk = xcur * INV2PI;
            dr = xk - floorf(xk);
            cd = __builtin_amdgcn_cosf(dr);
            sd = __builtin_amdgcn_sinf(dr);
            feats(&A_lds[(p + 1) & 1][0], xk, cd, sd);
        }
        __syncthreads();
    }

    // ---- store partials: part[chunk][b][j] ----
    // 32x32 C/D (m74/m101, verified R4): col = lane&31,
    // row = (v&3) + 8*(v>>2) + 4*(lane>>5)
    const int cb = wn * 64 + (lane & 31);
    const int rb = b0 + wm * 64 + 4 * (lane >> 5);
    float* pc = part + (size_t)chunk * (BATCH * ODIM);
    #pragma unroll
    for (int rt = 0; rt < 2; ++rt)
        #pragma unroll
        for (int f = 0; f < 2; ++f)
            #pragma unroll
            for (int v = 0; v < 16; ++v) {
                int r = rb + rt * 32 + (v & 3) + 8 * (v >> 2);
                pc[(size_t)r * ODIM + cb + f * 32] = acc[rt][f][v];
            }
}

__global__ void reduce_bias(const float4v* __restrict__ part,
                            const float4v* __restrict__ bias,
                            float4v* __restrict__ out)
{
    const int tid = blockIdx.x * 256 + threadIdx.x;   // 524288 float4s
    const int Q = BATCH * ODIM / 4;
    float4v r = part[tid];
    #pragma unroll
    for (int c = 1; c < NC; ++c) r += part[tid + c * Q];
    r += bias[tid & 63];
    out[tid] = r;
}

extern "C" void kernel_launch(void* const* d_in, const int* in_sizes, int n_in,
                              void* d_out, int out_size, void* d_ws, size_t ws_size,
                              hipStream_t stream)
{
    const float* x = (const float*)d_in[0];
    const float* W = (const float*)d_in[1];
    const float* bias = (const float*)d_in[2];
    float* out = (float*)d_out;

    const size_t bw_bytes = (size_t)RG_TOT * 256 * 16;   // 16.78 MB

    short* Bw = (short*)d_ws;
    float* part = (float*)((char*)d_ws + bw_bytes);      // 67.1 MB (ws>=84MB proven R3)

    prep_w<<<4096, 256, 0, stream>>>((const float4v*)W, (uint4v*)Bw);
    // 512 blocks = 2 blocks/CU (65.5 KB LDS, <=128 unified regs/wave)
    kan_main<<<(BATCH / BM) * NC, THREADS, 0, stream>>>(x, Bw, part);
    reduce_bias<<<(BATCH * ODIM / 4) / 256, 256, 0, stream>>>(
        (const float4v*)part, (const float4v*)bias, (float4v*)out);
}

// Round 8
// 171.248 us; speedup vs baseline: 2.0259x; 1.0195x over previous
//
#include <hip/hip_runtime.h>
#include <hip/hip_bf16.h>

#define BATCH 8192
#define IDIM 256
#define ODIM 256

#define NC 8
#define IPC 32            // i-values per K-chunk
#define BM 128            // rows per block
#define THREADS 512
#define RG_TOT 4096       // (2*IDIM*KGRID)/8
#define RS 131            // uint4-slot stride between rg rows (>=128 rows, odd pad)

typedef __attribute__((ext_vector_type(8))) short short8;
typedef __attribute__((ext_vector_type(4))) float float4v;
typedef __attribute__((ext_vector_type(16))) float float16v;
typedef __attribute__((ext_vector_type(4))) unsigned int uint4v;

#define INV2PI 0.15915494309189535f

// pack two f32 -> (bf16(c) | bf16(s)<<16), RTNE
__device__ __forceinline__ unsigned int bf16pack(float c, float s) {
    union { float f; unsigned int u; } a, b;
    a.f = c; b.f = s;
    unsigned int ua = a.u + (0x7fffu + ((a.u >> 16) & 1u));
    unsigned int ub = b.u + (0x7fffu + ((b.u >> 16) & 1u));
    return (ua >> 16) | (ub & 0xffff0000u);
}

// W[2][256][256][64] f32  ->  Bw[rg=4096][j=256][8] bf16, read-coalesced
__global__ void prep_w(const float4v* __restrict__ W, uint4v* __restrict__ Bw) {
    int tid = blockIdx.x * 256 + threadIdx.x;   // 1,048,576 threads
    int rg = tid & 4095;
    int j = tid >> 12;
    float4v c4 = W[j * 4096 + rg];
    float4v s4 = W[1048576 + j * 4096 + rg];
    uint4v o;
    o.x = bf16pack(c4.x, s4.x);
    o.y = bf16pack(c4.y, s4.y);
    o.z = bf16pack(c4.z, s4.z);
    o.w = bf16pack(c4.w, s4.w);
    Bw[rg * 256 + j] = o;
}

// 8 waves (2M x 4N), wave tile 64x64 via 32x32x16 MFMA (acc = 64 AGPR).
// feats(p+1) runs BEFORE MFMA(p) each iteration: VALU phase covers the
// i-boundary B-loads and co-resident waves' MFMA overlaps it.
__global__ __launch_bounds__(THREADS, 4) void kan_main(
    const float* __restrict__ x,
    const short* __restrict__ Bw,
    float* __restrict__ part)
{
    // per-i slab: [16 rg][RS=131 row-slots] uint4 = 32.75 KB; dbuf 65.5 KB
    __shared__ __align__(16) uint4v A_lds[2][16 * RS];

    const int bx = blockIdx.x;
    const int chunk = bx & 7;          // K-chunk == XCD id (512 blocks)
    const int mt = bx >> 3;            // M-tile 0..63
    const int b0 = mt * BM;
    const int i0 = chunk * IPC;
    const int t = threadIdx.x;
    const int lane = t & 63;
    const int wave = t >> 6;           // 0..7
    const int wm = wave >> 2;          // 0..1  (64-row half)
    const int wn = wave & 3;           // 0..3  (64-col quarter)

    const int frow = t >> 2;           // 0..127 feats row
    const int fsub = t & 3;            // 16 consecutive codes per thread

    const float* xp = x + (size_t)(b0 + frow) * IDIM + i0;

    // features for one i via Chebyshev recurrence: f_{m+1} = k2*f_m - f_{m-1}
    // (k2 = 2*cos(2*pi*x)); thread covers multipliers m0..m0+15 of its row.
    auto feats = [&](uint4v* buf, float xk, float k2) {
        const float m0 = (float)(fsub * 16 + 1);
        float r0 = xk * m0;       r0 -= floorf(r0);
        float r1 = xk * m0 + xk;  r1 -= floorf(r1);
        float ca = __builtin_amdgcn_cosf(r0);
        float sa = __builtin_amdgcn_sinf(r0);
        float cb = __builtin_amdgcn_cosf(r1);
        float sb = __builtin_amdgcn_sinf(r1);
        uint4v* sl = buf + (fsub * 4) * RS + frow;
        #pragma unroll
        for (int q = 0; q < 4; ++q) {
            uint4v o;
            #pragma unroll
            for (int e = 0; e < 4; ++e) {
                union { __hip_bfloat162 h2; unsigned int w; } cv;
                cv.h2 = __float22bfloat162_rn(make_float2(ca, sa));
                o[e] = cv.w;
                float cn = k2 * cb - ca;
                float sn = k2 * sb - sa;
                ca = cb; sa = sb; cb = cn; sb = sn;
            }
            sl[q * RS] = o;
        }
    };

    // B slot = rg*256 + col; rg = chunk*512 + g*2 + (lane>>5);
    // col = wn*64 + f*32 + (lane&31)   (layout verified R4/R7)
    const short8* Bp = (const short8*)Bw
        + (size_t)(chunk * 512 + (lane >> 5)) * 256 + wn * 64 + (lane & 31);

    // ---- prologue ----
    float xv = xp[0];
    float xk = xv * INV2PI;
    float dr = xk - floorf(xk);
    float k2 = 2.0f * __builtin_amdgcn_cosf(dr);
    feats(&A_lds[0][0], xk, k2);

    float xv_n = xp[1];

    short8 bB[2][2];
    bB[0][0] = Bp[0];       bB[0][1] = Bp[32];        // g = 0
    bB[1][0] = Bp[512];     bB[1][1] = Bp[512 + 32];  // g = 1

    __syncthreads();

    float16v acc[2][2];
    acc[0][0] = (float16v)(0.0f);
    acc[0][1] = (float16v)(0.0f);
    acc[1][0] = (float16v)(0.0f);
    acc[1][1] = (float16v)(0.0f);

    // A slot: (ks*2 + (lane>>5))*RS + wm*64 + rt*32 + (lane&31)
    const int abase = (lane >> 5) * RS + wm * 64 + (lane & 31);

    for (int p = 0; p < IPC; ++p) {
        // ---- feats for next i FIRST (covers B loads, overlaps other waves' MFMA)
        if (p + 1 < IPC) {
            float xkn = xv_n * INV2PI;
            float drn = xkn - floorf(xkn);
            float k2n = 2.0f * __builtin_amdgcn_cosf(drn);
            feats(&A_lds[(p + 1) & 1][0], xkn, k2n);
            xv_n = xp[(p + 2 < IPC) ? (p + 2) : (IPC - 1)];
        }
        // ---- MFMA over current buffer
        const short8* Ab = (const short8*)&A_lds[p & 1][0];
        __builtin_amdgcn_s_setprio(1);
        #pragma unroll
        for (int ks = 0; ks < 8; ++ks) {
            short8 a0 = Ab[(ks * 2) * RS + abase];
            short8 a1 = Ab[(ks * 2) * RS + abase + 32];
            acc[0][0] = __builtin_amdgcn_mfma_f32_32x32x16_bf16(a0, bB[ks & 1][0], acc[0][0], 0, 0, 0);
            acc[1][0] = __builtin_amdgcn_mfma_f32_32x32x16_bf16(a1, bB[ks & 1][0], acc[1][0], 0, 0, 0);
            acc[0][1] = __builtin_amdgcn_mfma_f32_32x32x16_bf16(a0, bB[ks & 1][1], acc[0][1], 0, 0, 0);
            acc[1][1] = __builtin_amdgcn_mfma_f32_32x32x16_bf16(a1, bB[ks & 1][1], acc[1][1], 0, 0, 0);
            // prefetch g = p*8 + ks + 2 into the slot just consumed (static ks&1)
            int g = p * 8 + ks + 2;
            if (g > 255) g = 255;                 // tail clamp, data unused
            bB[ks & 1][0] = Bp[(size_t)g * 512];
            bB[ks & 1][1] = Bp[(size_t)g * 512 + 32];
        }
        __builtin_amdgcn_s_setprio(0);
        __syncthreads();
    }

    // ---- store partials: part[chunk][b][j] ----
    // 32x32 C/D (m74/m101, verified R4/R7): col = lane&31,
    // row = (v&3) + 8*(v>>2) + 4*(lane>>5)
    const int cb = wn * 64 + (lane & 31);
    const int rb = b0 + wm * 64 + 4 * (lane >> 5);
    float* pc = part + (size_t)chunk * (BATCH * ODIM);
    #pragma unroll
    for (int rt = 0; rt < 2; ++rt)
        #pragma unroll
        for (int f = 0; f < 2; ++f)
            #pragma unroll
            for (int v = 0; v < 16; ++v) {
                int r = rb + rt * 32 + (v & 3) + 8 * (v >> 2);
                pc[(size_t)r * ODIM + cb + f * 32] = acc[rt][f][v];
            }
}

__global__ void reduce_bias(const float4v* __restrict__ part,
                            const float4v* __restrict__ bias,
                            float4v* __restrict__ out)
{
    const int tid = blockIdx.x * 256 + threadIdx.x;   // 524288 float4s
    const int Q = BATCH * ODIM / 4;
    float4v r = part[tid];
    #pragma unroll
    for (int c = 1; c < NC; ++c) r += part[tid + c * Q];
    r += bias[tid & 63];
    out[tid] = r;
}

extern "C" void kernel_launch(void* const* d_in, const int* in_sizes, int n_in,
                              void* d_out, int out_size, void* d_ws, size_t ws_size,
                              hipStream_t stream)
{
    const float* x = (const float*)d_in[0];
    const float* W = (const float*)d_in[1];
    const float* bias = (const float*)d_in[2];
    float* out = (float*)d_out;

    const size_t bw_bytes = (size_t)RG_TOT * 256 * 16;   // 16.78 MB

    short* Bw = (short*)d_ws;
    float* part = (float*)((char*)d_ws + bw_bytes);      // 67.1 MB (ws>=84MB proven R3)

    prep_w<<<4096, 256, 0, stream>>>((const float4v*)W, (uint4v*)Bw);
    // 512 blocks = 2 blocks/CU (65.5 KB LDS, <=128 unified regs/wave)
    kan_main<<<(BATCH / BM) * NC, THREADS, 0, stream>>>(x, Bw, part);
    reduce_bias<<<(BATCH * ODIM / 4) / 256, 256, 0, stream>>>(
        (const float4v*)part, (const float4v*)bias, (float4v*)out);
}